// Round 2
// baseline (278.982 us; speedup 1.0000x reference)
//
#include <hip/hip_runtime.h>

// Planar NF, fully fused single kernel — occupancy-first restructure.
//   p = X.W^T ; t_k = tanh(p_k + b_k + sum_{j<k} t_j G[k][j]) ; z = X + T.Uhat
//   G[k][j] = uhat_j.w_k = M1[k][j] + coef_j*M2[k][j],  M1=U.W^T, M2=W.W^T
//   c_k = w_k.uhat_k = softplus(w_k.u_k) - 1
// 512 threads, ROWS=128, LDS ~77KB -> 2 blocks/CU = 16 waves/CU (4/SIMD).
// Thread owns ONE row: X streamed from global (no LDS staging, no transpose).
// W/Uhat LDS reads are wave-uniform broadcasts; P/T in [k][r] layout = conflict-free.

#define B_ 65536
#define D_ 256
#define K_ 32
#define ROWS 128
#define NTHR 512
#define WT_STRIDE 36   // w table [d][k] stride (pad so gen-transpose writes are conflict-free)
#define US_STRIDE 260  // uhat [k][d] stride (reads are uniform broadcasts; 16B-aligned)
#define P_OFF 4096     // float offset of P inside wT region (T at 0), both [k][r] stride 128

__global__ __launch_bounds__(NTHR, 4) void nf_fused(const float* __restrict__ X,
                                                    const float* __restrict__ u_in,
                                                    const float* __restrict__ w_in,
                                                    const float* __restrict__ b_in,
                                                    float* __restrict__ out) {
  __shared__ float wT[256 * WT_STRIDE];  // 36864 B: w [d][k]; after phase1: T[k][r]@0, P[k][r]@P_OFF
  __shared__ float us[32 * US_STRIDE];   // 33280 B: uhat [k][d]
  __shared__ float Gm[32 * 33];          // M1 -> G (in place)
  __shared__ float Gm2[32 * 33];         // M2
  __shared__ float cs_s[32], coefs_s[32], bfs_s[32];

  const int t = threadIdx.x;
  const int row0 = blockIdx.x * ROWS;
  const int r = t & 127;   // this thread's row within the block tile
  const int ko = t >> 7;   // 0..3 : k-octet (phase 1) / col-octet*2 (phase 3)

  // ---------- step 0: stage w -> wT[d][k] (transpose); b -> bfs ----------
  {
    const int k = t & 31;
    const int d0 = (t >> 5) * 16;
    float4 wv4[4];
    const float4* wp = (const float4*)(w_in + k * 256 + d0);
#pragma unroll
    for (int q = 0; q < 4; ++q) wv4[q] = wp[q];
#pragma unroll
    for (int q = 0; q < 4; ++q) {
      const float* f = (const float*)&wv4[q];
#pragma unroll
      for (int i = 0; i < 4; ++i) wT[(d0 + q * 4 + i) * WT_STRIDE + k] = f[i];
    }
    if (t < 32) bfs_s[t] = b_in[t];
  }

  // ---------- step 1: M1[k][j]=u_j.w_k, M2[k][j]=w_j.w_k (global reads, L2-hot) ----------
  {
    const int j = t & 31;
    const int kg = t >> 5;  // 0..15 -> rows kg and kg+16
    const float4* uj = (const float4*)(u_in + j * 256);
    const float4* wj = (const float4*)(w_in + j * 256);
    const float4* wk0 = (const float4*)(w_in + kg * 256);
    const float4* wk1 = (const float4*)(w_in + (kg + 16) * 256);
    float m10 = 0.f, m11 = 0.f, m20 = 0.f, m21 = 0.f;
#pragma unroll 4
    for (int q = 0; q < 64; ++q) {
      float4 a = uj[q], bw = wj[q], c0 = wk0[q], c1 = wk1[q];
      m10 = fmaf(a.x, c0.x, m10); m10 = fmaf(a.y, c0.y, m10);
      m10 = fmaf(a.z, c0.z, m10); m10 = fmaf(a.w, c0.w, m10);
      m11 = fmaf(a.x, c1.x, m11); m11 = fmaf(a.y, c1.y, m11);
      m11 = fmaf(a.z, c1.z, m11); m11 = fmaf(a.w, c1.w, m11);
      m20 = fmaf(bw.x, c0.x, m20); m20 = fmaf(bw.y, c0.y, m20);
      m20 = fmaf(bw.z, c0.z, m20); m20 = fmaf(bw.w, c0.w, m20);
      m21 = fmaf(bw.x, c1.x, m21); m21 = fmaf(bw.y, c1.y, m21);
      m21 = fmaf(bw.z, c1.z, m21); m21 = fmaf(bw.w, c1.w, m21);
    }
    Gm[kg * 33 + j] = m10;
    Gm[(kg + 16) * 33 + j] = m11;
    Gm2[kg * 33 + j] = m20;
    Gm2[(kg + 16) * 33 + j] = m21;
  }
  __syncthreads();

  // ---------- step 2: coefs, c from diagonals ----------
  if (t < 32) {
    float wu = Gm[t * 33 + t];
    float ww = Gm2[t * 33 + t];
    float sp = fmaxf(wu, 0.f) + log1pf(__expf(-fabsf(wu)));
    coefs_s[t] = (sp - 1.f - wu) / ww;
    cs_s[t] = sp - 1.f;
  }
  __syncthreads();

  // ---------- step 3: G in place; uhat -> us ----------
  {
    {
      const int k0 = t >> 5, j0 = t & 31;  // entry t
      Gm[k0 * 33 + j0] = fmaf(coefs_s[j0], Gm2[k0 * 33 + j0], Gm[k0 * 33 + j0]);
      const int k1 = k0 + 16;              // entry t+512
      Gm[k1 * 33 + j0] = fmaf(coefs_s[j0], Gm2[k1 * 33 + j0], Gm[k1 * 33 + j0]);
    }
    const int k = t >> 4;
    const int d0 = (t & 15) * 16;
    const float ck = coefs_s[k];
    const float4* up = (const float4*)(u_in + k * 256 + d0);
    const float4* wp = (const float4*)(w_in + k * 256 + d0);
    float4* ud = (float4*)&us[k * US_STRIDE + d0];
#pragma unroll
    for (int q = 0; q < 4; ++q) {
      float4 uv = up[q], wv = wp[q];
      uv.x = fmaf(ck, wv.x, uv.x);
      uv.y = fmaf(ck, wv.y, uv.y);
      uv.z = fmaf(ck, wv.z, uv.z);
      uv.w = fmaf(ck, wv.w, uv.w);
      ud[q] = uv;
    }
  }
  __syncthreads();

  // ---------- phase 1: p[8] = X[row] . w[:, ko*8 .. ko*8+8) ----------
  float p[8];
#pragma unroll
  for (int b2 = 0; b2 < 8; ++b2) p[b2] = 0.f;
  {
    const int kb = ko * 8;
    const float4* xrow = (const float4*)(X + (size_t)(row0 + r) * 256);
#pragma unroll 2
    for (int c = 0; c < 16; ++c) {
      float4 xq[4];
#pragma unroll
      for (int q = 0; q < 4; ++q) xq[q] = xrow[c * 4 + q];
#pragma unroll
      for (int i = 0; i < 16; ++i) {
        const int d = c * 16 + i;
        float4 w0 = *(const float4*)&wT[d * WT_STRIDE + kb];      // wave-uniform broadcast
        float4 w1 = *(const float4*)&wT[d * WT_STRIDE + kb + 4];  // wave-uniform broadcast
        const float xd = ((const float*)xq)[i];
        p[0] = fmaf(xd, w0.x, p[0]);
        p[1] = fmaf(xd, w0.y, p[1]);
        p[2] = fmaf(xd, w0.z, p[2]);
        p[3] = fmaf(xd, w0.w, p[3]);
        p[4] = fmaf(xd, w1.x, p[4]);
        p[5] = fmaf(xd, w1.y, p[5]);
        p[6] = fmaf(xd, w1.z, p[6]);
        p[7] = fmaf(xd, w1.w, p[7]);
      }
    }
  }
  __syncthreads();  // all w reads done; wT region reusable

  // ---------- dump P[k][r] (conflict-free: lanes span consecutive r) ----------
  {
    const int kb = ko * 8;
#pragma unroll
    for (int b2 = 0; b2 < 8; ++b2) wT[P_OFF + (kb + b2) * 128 + r] = p[b2];
  }
  __syncthreads();

  // ---------- recurrence: one row per thread (t < 128) ----------
  if (t < 128) {
    float pfull[32];
#pragma unroll
    for (int j = 0; j < 32; ++j) pfull[j] = wT[P_OFF + j * 128 + t] + bfs_s[j];
    float tvv[32];
#pragma unroll
    for (int k = 0; k < 32; ++k) {
      float la = pfull[k], lb = 0.f;
      const float* gp = &Gm[k * 33];
#pragma unroll
      for (int j = 0; j + 1 < k; j += 2) {
        la = fmaf(tvv[j], gp[j], la);
        lb = fmaf(tvv[j + 1], gp[j + 1], lb);
      }
      if (k & 1) la = fmaf(tvv[k - 1], gp[k - 1], la);
      float lin = la + lb;
      float e = __expf(2.f * lin);
      float tk = 1.f - 2.f / (e + 1.f);
      tvv[k] = tk;
      wT[k * 128 + t] = tk;  // T[k][r]
      float val = fabsf(fmaf(1.f - tk * tk, cs_s[k], 1.f)) + 1e-8f;
      out[(size_t)B_ * D_ + (size_t)k * B_ + row0 + t] = __logf(val);
    }
  }
  __syncthreads();

  // ---------- phase 3: z[row] = X[row] + T[row] . Uhat  (2 passes x 32 cols) ----------
  for (int pass = 0; pass < 2; ++pass) {
    const int c0 = ko * 64 + pass * 32;
    float acc[32];
    {
      const float4* xrow = (const float4*)(X + (size_t)(row0 + r) * 256 + c0);
#pragma unroll
      for (int q = 0; q < 8; ++q) {
        float4 v = xrow[q];
        acc[q * 4 + 0] = v.x;
        acc[q * 4 + 1] = v.y;
        acc[q * 4 + 2] = v.z;
        acc[q * 4 + 3] = v.w;
      }
    }
#pragma unroll 2
    for (int k = 0; k < 32; ++k) {
      float tk = wT[k * 128 + r];                              // lanes: consecutive r, conflict-free
      const float4* uu = (const float4*)&us[k * US_STRIDE + c0];  // wave-uniform broadcast
#pragma unroll
      for (int q = 0; q < 8; ++q) {
        float4 uv = uu[q];
        acc[q * 4 + 0] = fmaf(tk, uv.x, acc[q * 4 + 0]);
        acc[q * 4 + 1] = fmaf(tk, uv.y, acc[q * 4 + 1]);
        acc[q * 4 + 2] = fmaf(tk, uv.z, acc[q * 4 + 2]);
        acc[q * 4 + 3] = fmaf(tk, uv.w, acc[q * 4 + 3]);
      }
    }
    float4* orow = (float4*)(out + (size_t)(row0 + r) * 256 + c0);
#pragma unroll
    for (int q = 0; q < 8; ++q)
      orow[q] = make_float4(acc[q * 4 + 0], acc[q * 4 + 1], acc[q * 4 + 2], acc[q * 4 + 3]);
  }
}

extern "C" void kernel_launch(void* const* d_in, const int* in_sizes, int n_in,
                              void* d_out, int out_size, void* d_ws, size_t ws_size,
                              hipStream_t stream) {
  const float* X = (const float*)d_in[0];
  // d_in[1] = h : unused by the math
  const float* u = (const float*)d_in[2];
  const float* w = (const float*)d_in[3];
  const float* b = (const float*)d_in[4];
  float* out = (float*)d_out;

  nf_fused<<<B_ / ROWS, NTHR, 0, stream>>>(X, u, w, b, out);
}

// Round 3
// 204.458 us; speedup vs baseline: 1.3645x; 1.3645x over previous
//
#include <hip/hip_runtime.h>

// Planar NF v3: two kernels.
//  nf_gen (1 block): Wt=[d][k], uhat, G[k][j]=uhat_j.w_k, c_k -> workspace.
//  nf_fused (512 blocks, 256 thr, ROWS=128): LDS = wT 32K (->P+T) + us 32K + Xs 16K
//   = 81920 B exactly -> 2 blocks/CU (8 waves/CU). 4-row register blocking:
//   phase1 4r x 4k (2 LDS reads / 16 FMA), phase3 4r x 8c (3 LDS reads / 32 FMA).
//   X staged coalesced with additive bank swizzle; all broadcasts conflict-free.

#define B_ 65536
#define D_ 256
#define ROWS 128
#define GRID (B_ / ROWS)

#define WS_WT 0
#define WS_UH 8192
#define WS_G  16384
#define WS_C  17408

// additive row swizzle for Xs [32 c][128 r]: distinct bank offsets across cl
#define SW(c) (4 * (((c) + ((c) >> 3)) & 7))

__global__ __launch_bounds__(256) void nf_gen(const float* __restrict__ u_in,
                                              const float* __restrict__ w_in,
                                              float* __restrict__ ws) {
  __shared__ float wTg[8192];  // [d][k]
  __shared__ float ug[8192];   // [j][d]
  __shared__ float wu_s[32], ww_s[32], coefs_s[32];
  const int t = threadIdx.x;
  {
    const int k = t & 31, d0 = (t >> 5) * 32;
    const float4* wp = (const float4*)(w_in + k * 256 + d0);
#pragma unroll
    for (int q = 0; q < 8; ++q) {
      float4 v = wp[q];
      wTg[(d0 + q * 4 + 0) * 32 + k] = v.x;
      wTg[(d0 + q * 4 + 1) * 32 + k] = v.y;
      wTg[(d0 + q * 4 + 2) * 32 + k] = v.z;
      wTg[(d0 + q * 4 + 3) * 32 + k] = v.w;
    }
#pragma unroll
    for (int q = 0; q < 8; ++q)
      ((float4*)ug)[t + 256 * q] = ((const float4*)u_in)[t + 256 * q];
  }
  __syncthreads();
  const int k = t & 31, jg = t >> 5;  // this thread: row k, cols jg*4..+4
  float m1[4] = {0.f, 0.f, 0.f, 0.f}, m2[4] = {0.f, 0.f, 0.f, 0.f};
#pragma unroll 4
  for (int dc = 0; dc < 64; ++dc) {
    float wk[4];
    float4 wj[4], uj[4];
#pragma unroll
    for (int i = 0; i < 4; ++i) wk[i] = wTg[(dc * 4 + i) * 32 + k];
#pragma unroll
    for (int i = 0; i < 4; ++i) wj[i] = *(const float4*)&wTg[(dc * 4 + i) * 32 + jg * 4];
#pragma unroll
    for (int i = 0; i < 4; ++i) uj[i] = *(const float4*)&ug[(jg * 4 + i) * 256 + dc * 4];
#pragma unroll
    for (int i = 0; i < 4; ++i) {
      m1[i] = fmaf(uj[i].x, wk[0], m1[i]);
      m1[i] = fmaf(uj[i].y, wk[1], m1[i]);
      m1[i] = fmaf(uj[i].z, wk[2], m1[i]);
      m1[i] = fmaf(uj[i].w, wk[3], m1[i]);
    }
    const float* w0 = (const float*)&wj[0];
    const float* w1 = (const float*)&wj[1];
    const float* w2 = (const float*)&wj[2];
    const float* w3 = (const float*)&wj[3];
#pragma unroll
    for (int i = 0; i < 4; ++i) {
      m2[i] = fmaf(w0[i], wk[0], m2[i]);
      m2[i] = fmaf(w1[i], wk[1], m2[i]);
      m2[i] = fmaf(w2[i], wk[2], m2[i]);
      m2[i] = fmaf(w3[i], wk[3], m2[i]);
    }
  }
  if ((k >> 2) == jg) {  // holds diagonal element j==k
    wu_s[k] = m1[k & 3];
    ww_s[k] = m2[k & 3];
  }
  __syncthreads();
  if (t < 32) {
    float wu = wu_s[t], ww = ww_s[t];
    float sp = fmaxf(wu, 0.f) + log1pf(__expf(-fabsf(wu)));
    coefs_s[t] = (sp - 1.f - wu) / ww;
    ws[WS_C + t] = sp - 1.f;  // c_k = w_k.uhat_k
  }
  __syncthreads();
#pragma unroll
  for (int i = 0; i < 4; ++i)
    ws[WS_G + k * 32 + jg * 4 + i] = fmaf(coefs_s[jg * 4 + i], m2[i], m1[i]);
  {
    const int k2 = t >> 3, d0 = (t & 7) * 32;
    const float ck = coefs_s[k2];
    const float4* up = (const float4*)(u_in + k2 * 256 + d0);
    const float4* wp2 = (const float4*)(w_in + k2 * 256 + d0);
    float4* od = (float4*)(ws + WS_UH + k2 * 256 + d0);
#pragma unroll
    for (int q = 0; q < 8; ++q) {
      float4 uv = up[q], wv = wp2[q];
      uv.x = fmaf(ck, wv.x, uv.x);
      uv.y = fmaf(ck, wv.y, uv.y);
      uv.z = fmaf(ck, wv.z, uv.z);
      uv.w = fmaf(ck, wv.w, uv.w);
      od[q] = uv;
    }
  }
#pragma unroll
  for (int q = 0; q < 8; ++q)
    ((float4*)(ws + WS_WT))[t + 256 * q] = ((const float4*)wTg)[t + 256 * q];
}

__global__ __launch_bounds__(256) void nf_fused(const float* __restrict__ X,
                                                const float* __restrict__ b_in,
                                                const float* __restrict__ ws,
                                                float* __restrict__ out) {
  __shared__ float wT[8192];  // Wt [d][k]; after phase1: P@0 [32][128], T@4096 [32][128]
  __shared__ float us[8192];  // uhat [k][d]
  __shared__ float Xs[4096];  // X stage [32 c][128 r] swizzled; later G(33-pad)/c/b
  const int t = threadIdx.x;
  const int row0 = blockIdx.x * ROWS;
  const int xoff = (t >> 6) * 32 + ((t >> 3) & 7) * 4;  // 4-row base
  const int kq4 = (t & 7) * 4;                          // phase1 k base
  const int row_ld = t >> 3;                            // staging row 0..31
  const int cl = t & 7;                                 // staging col quad

  // stage tables (coalesced, L2/L3-hot)
#pragma unroll
  for (int q = 0; q < 8; ++q)
    ((float4*)wT)[t + 256 * q] = ((const float4*)(ws + WS_WT))[t + 256 * q];
#pragma unroll
  for (int q = 0; q < 8; ++q)
    ((float4*)us)[t + 256 * q] = ((const float4*)(ws + WS_UH))[t + 256 * q];

  float4 pf[4];
  auto load_stage = [&](int s) {
#pragma unroll
    for (int p = 0; p < 4; ++p)
      pf[p] = *(const float4*)(X + (size_t)(row0 + p * 32 + row_ld) * 256 + s * 32 + cl * 4);
  };
  auto store_stage = [&]() {
#pragma unroll
    for (int p = 0; p < 4; ++p) {
      const float f[4] = {pf[p].x, pf[p].y, pf[p].z, pf[p].w};
#pragma unroll
      for (int i = 0; i < 4; ++i) {
        const int c = cl * 4 + i;
        Xs[c * 128 + ((p * 32 + row_ld + SW(c)) & 127)] = f[i];
      }
    }
  };

  load_stage(0);
  __syncthreads();  // wT/us visible

  // ---------------- phase 1: p[4r][4k] = X . w ----------------
  float p[4][4];
#pragma unroll
  for (int a = 0; a < 4; ++a)
#pragma unroll
    for (int b = 0; b < 4; ++b) p[a][b] = 0.f;

  for (int s = 0; s < 8; ++s) {
    store_stage();
    __syncthreads();
    if (s < 7) load_stage(s + 1);
#pragma unroll 8
    for (int dl = 0; dl < 32; ++dl) {
      float4 xv = *(const float4*)&Xs[dl * 128 + ((xoff + SW(dl)) & 127)];  // 4 rows
      float4 wv = *(const float4*)&wT[(s * 32 + dl) * 32 + kq4];            // 4 k (bcast)
      const float xr[4] = {xv.x, xv.y, xv.z, xv.w};
      const float wk[4] = {wv.x, wv.y, wv.z, wv.w};
#pragma unroll
      for (int a = 0; a < 4; ++a)
#pragma unroll
        for (int b = 0; b < 4; ++b) p[a][b] = fmaf(xr[a], wk[b], p[a][b]);
    }
    __syncthreads();
  }

  // ---------------- P dump [k][r]; stage G/c/b into Xs region ----------------
#pragma unroll
  for (int b = 0; b < 4; ++b)
    *(float4*)&wT[(kq4 + b) * 128 + xoff] = make_float4(p[0][b], p[1][b], p[2][b], p[3][b]);
#pragma unroll
  for (int i = 0; i < 4; ++i) {
    const int e = t * 4 + i;
    Xs[(e >> 5) * 33 + (e & 31)] = ws[WS_G + e];
  }
  if (t < 32) {
    Xs[1536 + t] = ws[WS_C + t];
    Xs[1568 + t] = b_in[t];
  }
  __syncthreads();

  // ---------------- recurrence: one row per thread ----------------
  if (t < 128) {
    float pfull[32];
#pragma unroll
    for (int j = 0; j < 32; ++j) pfull[j] = wT[j * 128 + t] + Xs[1568 + j];
    float tvv[32];
#pragma unroll
    for (int kk = 0; kk < 32; ++kk) {
      float la = pfull[kk], lb = 0.f;
      const float* gp = &Xs[kk * 33];
#pragma unroll
      for (int j = 0; j + 1 < kk; j += 2) {
        la = fmaf(tvv[j], gp[j], la);
        lb = fmaf(tvv[j + 1], gp[j + 1], lb);
      }
      if (kk & 1) la = fmaf(tvv[kk - 1], gp[kk - 1], la);
      float lin = la + lb;
      float e = __expf(2.f * lin);
      float tk = 1.f - 2.f / (e + 1.f);
      tvv[kk] = tk;
      wT[4096 + kk * 128 + t] = tk;  // T [k][r]
      float val = fabsf(fmaf(1.f - tk * tk, Xs[1536 + kk], 1.f)) + 1e-8f;
      out[(size_t)B_ * D_ + (size_t)kk * B_ + row0 + t] = __logf(val);
    }
  }
  __syncthreads();

  // ---------------- phase 3: z = X + T . uhat (4r x 8c per thread) ----------------
  const int cq8 = (t & 7) * 8;
  for (int cb = 0; cb < 4; ++cb) {
    const int c0 = cb * 64 + cq8;
    float acc[4][8];
#pragma unroll
    for (int a = 0; a < 4; ++a) {
      const float4 x0 = *(const float4*)(X + (size_t)(row0 + xoff + a) * 256 + c0);
      const float4 x1 = *(const float4*)(X + (size_t)(row0 + xoff + a) * 256 + c0 + 4);
      acc[a][0] = x0.x; acc[a][1] = x0.y; acc[a][2] = x0.z; acc[a][3] = x0.w;
      acc[a][4] = x1.x; acc[a][5] = x1.y; acc[a][6] = x1.z; acc[a][7] = x1.w;
    }
#pragma unroll 8
    for (int kk = 0; kk < 32; ++kk) {
      float4 t4 = *(const float4*)&wT[4096 + kk * 128 + xoff];  // 4 rows of T
      float4 u0 = *(const float4*)&us[kk * 256 + c0];           // 8 uhat cols (bcast)
      float4 u1 = *(const float4*)&us[kk * 256 + c0 + 4];
      const float tr[4] = {t4.x, t4.y, t4.z, t4.w};
      const float uk[8] = {u0.x, u0.y, u0.z, u0.w, u1.x, u1.y, u1.z, u1.w};
#pragma unroll
      for (int a = 0; a < 4; ++a)
#pragma unroll
        for (int b = 0; b < 8; ++b) acc[a][b] = fmaf(tr[a], uk[b], acc[a][b]);
    }
#pragma unroll
    for (int a = 0; a < 4; ++a) {
      float4* op = (float4*)(out + (size_t)(row0 + xoff + a) * 256 + c0);
      op[0] = make_float4(acc[a][0], acc[a][1], acc[a][2], acc[a][3]);
      op[1] = make_float4(acc[a][4], acc[a][5], acc[a][6], acc[a][7]);
    }
  }
}

extern "C" void kernel_launch(void* const* d_in, const int* in_sizes, int n_in,
                              void* d_out, int out_size, void* d_ws, size_t ws_size,
                              hipStream_t stream) {
  const float* X = (const float*)d_in[0];
  // d_in[1] = h : unused by the math
  const float* u = (const float*)d_in[2];
  const float* w = (const float*)d_in[3];
  const float* b = (const float*)d_in[4];
  float* out = (float*)d_out;
  float* ws = (float*)d_ws;

  nf_gen<<<1, 256, 0, stream>>>(u, w, ws);
  nf_fused<<<GRID, 256, 0, stream>>>(X, b, ws, out);
}